// Round 6
// baseline (23.834 us; speedup 1.0000x reference)
//
#include <hip/hip_runtime.h>
#include <stdint.h>

// InstanceLoss: loss = sum_{lab[i]==lab[j], i!=j} ||e_i - e_j + EPS|| / (N*(N-1))
// dist^2 = n_i + n_j - 2*G_ij (EPS terms ~1e-10, far below the 7e-3 threshold).
// Labels in [0,64) -> only within-group pairs. Gram is symmetric per group, so:
// grid = 128 blocks = 64 groups x 2 row-halves. Each block:
//   - reads labels into REGISTERS (coalesced), ballot-rank scan -> rowlist
//   - stages the group's 256 rows ONCE (f32->bf16, XOR-granule-swizzled LDS)
//   - row norms from staged bf16 (consistent with MFMA gram)
//   - computes a 128x256 slab of the gram (rows = its half, cols = all),
//     so each ordered pair (i,j) is produced exactly once across the 2 blocks
//   - fused dist+mask+reduce; ticket; last block reduces deterministically.

#define NROWS 8192
#define DDIM 256
#define NLAB 64
#define NBLK (NLAB * 2)

typedef __attribute__((ext_vector_type(8))) short bfrag8;
typedef __attribute__((ext_vector_type(4))) float f32x4;

__device__ __forceinline__ unsigned short f2bf(float f) {
  unsigned u = __float_as_uint(f);
  u += 0x7FFFu + ((u >> 16) & 1u);   // RNE
  return (unsigned short)(u >> 16);
}

__global__ void __launch_bounds__(512)
k_fused(const float* __restrict__ E, const int* __restrict__ lab,
        float* __restrict__ partials, unsigned* __restrict__ counter,
        float* __restrict__ out, double invn) {
  // 256 rows x 256 bf16 (512 B rows; granule g of row r stored at slot g^(r&15))
  __shared__ __align__(16) char Xs[256 * 512];   // 128 KB
  __shared__ int rowlistS[256];
  __shared__ float qS[256];
  __shared__ int wcntS[8];
  __shared__ float wsum[8];
  __shared__ int lastS;

  const int bid = blockIdx.x;
  const int g = bid >> 1, h = bid & 1;           // group, row-half
  const int t = threadIdx.x, l = t & 63, w = t >> 6;   // 8 waves

  // ---- labels -> registers: wave w, lane l holds lab[(w*16+i)*64 + l] ----
  int lv[16];
  #pragma unroll
  for (int i = 0; i < 16; ++i)
    lv[i] = lab[(w * 16 + i) * 64 + l];          // coalesced 256B per chunk

  // pass A: per-wave own-label count
  int cntw = 0;
  #pragma unroll
  for (int i = 0; i < 16; ++i)
    cntw += (int)__popcll(__ballot(lv[i] == g));
  if (l == 0) wcntS[w] = cntw;
  if (t == 0) rowlistS[0] = 0;                   // n==0 safety
  __syncthreads();
  int n_total = 0, base = 0;
  #pragma unroll
  for (int w2 = 0; w2 < 8; ++w2) {
    const int c = wcntS[w2];
    n_total += c;
    base += (w2 < w) ? c : 0;
  }
  // pass B: global ranks -> rowlist (original row indices, grouped order)
  #pragma unroll
  for (int i = 0; i < 16; ++i) {
    const unsigned long long m = __ballot(lv[i] == g);
    if (lv[i] == g) {
      const int rank = base + (int)__popcll(m & ((1ull << l) - 1ull));
      if (rank < 256) rowlistS[rank] = (w * 16 + i) * 64 + l;
    }
    base += (int)__popcll(m);
  }
  const int n = min(n_total, 256);
  __syncthreads();                               // rowlist ready

  // ---- stage 256 rows once: f32 -> bf16, XOR-swizzled ds_write ----
  // wave w stages rows w*32..w*32+31; lane l covers elems 4l..4l+3.
  const int gsw = l >> 1;                        // 16B granule 0..31
  const int half8 = (l & 1) * 8;                 // byte offset in granule
  #pragma unroll 4
  for (int r = w * 32; r < w * 32 + 32; ++r) {
    const int grow = rowlistS[(r < n) ? r : 0];
    const float4 v = *reinterpret_cast<const float4*>(E + (size_t)grow * DDIM + l * 4);
    ushort4 b4;
    b4.x = f2bf(v.x); b4.y = f2bf(v.y); b4.z = f2bf(v.z); b4.w = f2bf(v.w);
    *reinterpret_cast<ushort4*>(Xs + r * 512 + ((gsw ^ (r & 15)) << 4) + half8) = b4;
  }
  __syncthreads();

  // ---- per-row sumsq from staged bf16 (2 threads per row) ----
  {
    const int r = t >> 1, hf = t & 1;
    float q = 0.f;
    #pragma unroll
    for (int i = 0; i < 16; ++i) {
      const int gidx = hf * 16 + i;
      const bfrag8 v = *reinterpret_cast<const bfrag8*>(
          Xs + r * 512 + ((gidx ^ (r & 15)) << 4));
      #pragma unroll
      for (int e = 0; e < 8; ++e) {
        const float f = __uint_as_float(((unsigned)(unsigned short)v[e]) << 16);
        q = fmaf(f, f, q);
      }
    }
    q += __shfl_xor(q, 1);
    if (hf == 0) qS[r] = q;
  }
  __syncthreads();

  // ---- MFMA slab: rows h*128..+128 x cols 0..256; 8 waves as 2x4 ----
  // per wave 64x64 output = 4x4 frags of 16x16, K=256 in 8 steps
  const int wr = w >> 2, wc = w & 3;
  const int colsel = l & 15;
  const int ksel = l >> 4;

  f32x4 acc[4][4];
  const f32x4 zero = {0.f, 0.f, 0.f, 0.f};
  #pragma unroll
  for (int m = 0; m < 4; ++m)
    #pragma unroll
    for (int nn = 0; nn < 4; ++nn)
      acc[m][nn] = zero;

  #pragma unroll
  for (int kk = 0; kk < 8; ++kk) {
    bfrag8 af[4], bf[4];
    #pragma unroll
    for (int m = 0; m < 4; ++m) {
      const int row = h * 128 + wr * 64 + m * 16 + colsel;
      const int gidx = (kk * 4 + ksel) ^ (row & 15);
      af[m] = *reinterpret_cast<const bfrag8*>(Xs + row * 512 + (gidx << 4));
    }
    #pragma unroll
    for (int nn = 0; nn < 4; ++nn) {
      const int row = wc * 64 + nn * 16 + colsel;
      const int gidx = (kk * 4 + ksel) ^ (row & 15);
      bf[nn] = *reinterpret_cast<const bfrag8*>(Xs + row * 512 + (gidx << 4));
    }
    #pragma unroll
    for (int m = 0; m < 4; ++m)
      #pragma unroll
      for (int nn = 0; nn < 4; ++nn)
        acc[m][nn] = __builtin_amdgcn_mfma_f32_16x16x32_bf16(af[m], bf[nn],
                                                             acc[m][nn], 0, 0, 0);
  }

  // ---- epilogue: dist + validity/diag mask + reduce ----
  // C layout: col(lane&15)=B row, row((lane>>4)*4+reg)=A row [verified r1-5]
  float lsum = 0.f;
  #pragma unroll
  for (int m = 0; m < 4; ++m) {
    const int ib = h * 128 + wr * 64 + m * 16 + ksel * 4;  // i_local base
    const float q0 = qS[ib], q1 = qS[ib + 1], q2 = qS[ib + 2], q3 = qS[ib + 3];
    #pragma unroll
    for (int nn = 0; nn < 4; ++nn) {
      const int jb = wc * 64 + nn * 16 + colsel;           // j_local
      const bool jv = jb < n;
      const float qj = qS[jb];
      const f32x4 a = acc[m][nn];
      const float d0 = __builtin_amdgcn_sqrtf(fmaxf(q0 + qj - 2.f * a[0], 0.f));
      const float d1 = __builtin_amdgcn_sqrtf(fmaxf(q1 + qj - 2.f * a[1], 0.f));
      const float d2 = __builtin_amdgcn_sqrtf(fmaxf(q2 + qj - 2.f * a[2], 0.f));
      const float d3 = __builtin_amdgcn_sqrtf(fmaxf(q3 + qj - 2.f * a[3], 0.f));
      if (jv) {
        lsum += (ib + 0 < n && ib + 0 != jb) ? d0 : 0.f;
        lsum += (ib + 1 < n && ib + 1 != jb) ? d1 : 0.f;
        lsum += (ib + 2 < n && ib + 2 != jb) ? d2 : 0.f;
        lsum += (ib + 3 < n && ib + 3 != jb) ? d3 : 0.f;
      }
    }
  }
  #pragma unroll
  for (int o = 32; o; o >>= 1) lsum += __shfl_down(lsum, o);
  if (l == 0) wsum[w] = lsum;
  __syncthreads();
  const float blocksum = wsum[0] + wsum[1] + wsum[2] + wsum[3] +
                         wsum[4] + wsum[5] + wsum[6] + wsum[7];

  // ---- publish partial + ticket; last block reduces in fixed order ----
  if (t == 0) {
    __hip_atomic_store(&partials[bid], blocksum, __ATOMIC_RELAXED,
                       __HIP_MEMORY_SCOPE_AGENT);
    const unsigned old = __hip_atomic_fetch_add(counter, 1u, __ATOMIC_ACQ_REL,
                                                __HIP_MEMORY_SCOPE_AGENT);
    lastS = (old == NBLK - 1) ? 1 : 0;
  }
  __syncthreads();
  if (lastS && t < 64) {
    const float p0 = __hip_atomic_load(&partials[t], __ATOMIC_RELAXED,
                                       __HIP_MEMORY_SCOPE_AGENT);
    const float p1 = __hip_atomic_load(&partials[t + 64], __ATOMIC_RELAXED,
                                       __HIP_MEMORY_SCOPE_AGENT);
    double s = (double)p0 + (double)p1;
    #pragma unroll
    for (int o = 32; o; o >>= 1) s += __shfl_down(s, o);
    if (t == 0) out[0] = (float)(s * invn);
  }
}

extern "C" void kernel_launch(void* const* d_in, const int* in_sizes, int n_in,
                              void* d_out, int out_size, void* d_ws, size_t ws_size,
                              hipStream_t stream) {
  const float* E = (const float*)d_in[0];
  const int* lab = (const int*)d_in[1];
  float* out = (float*)d_out;
  (void)n_in; (void)in_sizes; (void)out_size; (void)ws_size;

  char* ws = (char*)d_ws;
  float* partials = (float*)ws; ws += NBLK * sizeof(float);
  unsigned* counter = (unsigned*)ws;

  hipMemsetAsync(counter, 0, sizeof(unsigned), stream);  // graph-capturable node
  const double invn = 1.0 / ((double)NROWS * (double)(NROWS - 1));
  k_fused<<<NBLK, 512, 0, stream>>>(E, lab, partials, counter, out, invn);
}

// Round 7
// 23.652 us; speedup vs baseline: 1.0077x; 1.0077x over previous
//
#include <hip/hip_runtime.h>
#include <stdint.h>

// InstanceLoss: loss = sum_{lab[i]==lab[j], i!=j} ||e_i - e_j + EPS|| / (N*(N-1))
// dist^2 = n_i + n_j - 2*G_ij (EPS terms ~1e-10, far below the 7e-3 threshold).
// Labels in [0,64) -> only within-group pairs. All blocks run concurrently, so
// total time ~= one block's serial latency chain -> minimize chain length:
// grid = 256 blocks (64 groups x 4 ordered half-pairs (hi,hj)), 1024 threads.
// Each block: label ballot-scan -> rowlist; stage 128 A-rows + 128 B-rows
// (8+8 rows/wave, interleaved deep-unrolled loads) f32->bf16 into swizzled
// LDS; row norms from staged bf16; 128x128 gram slab via MFMA; fused
// dist+mask+reduce; ticket; last block reduces 256 partials deterministically.

#define NROWS 8192
#define DDIM 256
#define NLAB 64
#define NBLK (NLAB * 4)

typedef __attribute__((ext_vector_type(8))) short bfrag8;
typedef __attribute__((ext_vector_type(4))) float f32x4;

__device__ __forceinline__ unsigned short f2bf(float f) {
  unsigned u = __float_as_uint(f);
  u += 0x7FFFu + ((u >> 16) & 1u);   // RNE
  return (unsigned short)(u >> 16);
}

__global__ void __launch_bounds__(1024)
k_fused(const float* __restrict__ E, const int* __restrict__ lab,
        float* __restrict__ partials, unsigned* __restrict__ counter,
        float* __restrict__ out, double invn) {
  // 128 rows x 256 bf16 each (512 B rows; granule g of row r at slot g^(r&15))
  __shared__ __align__(16) char As[128 * 512];   // 64 KB
  __shared__ __align__(16) char Bs[128 * 512];   // 64 KB
  __shared__ int rowlistS[256];
  __shared__ float qA[128], qB[128];
  __shared__ int wcntS[16];
  __shared__ float wsum[16];
  __shared__ int lastS;

  const int bid = blockIdx.x;
  const int g = bid >> 2, hi = (bid >> 1) & 1, hj = bid & 1;
  const int t = threadIdx.x, l = t & 63, w = t >> 6;   // 16 waves

  // ---- labels -> registers: wave w owns chunks w*8..w*8+7 (64 rows each) ----
  int lv[8];
  #pragma unroll
  for (int i = 0; i < 8; ++i)
    lv[i] = lab[(w * 8 + i) * 64 + l];              // coalesced 256B per chunk

  int cntw = 0;
  #pragma unroll
  for (int i = 0; i < 8; ++i)
    cntw += (int)__popcll(__ballot(lv[i] == g));
  if (l == 0) wcntS[w] = cntw;
  if (t == 0) rowlistS[0] = 0;                      // n==0 safety
  __syncthreads();
  int n_total = 0, base = 0;
  #pragma unroll
  for (int w2 = 0; w2 < 16; ++w2) {
    const int c = wcntS[w2];
    n_total += c;
    base += (w2 < w) ? c : 0;
  }
  #pragma unroll
  for (int i = 0; i < 8; ++i) {
    const unsigned long long m = __ballot(lv[i] == g);
    if (lv[i] == g) {
      const int rank = base + (int)__popcll(m & ((1ull << l) - 1ull));
      if (rank < 256) rowlistS[rank] = (w * 8 + i) * 64 + l;
    }
    base += (int)__popcll(m);
  }
  const int n = min(n_total, 256);
  __syncthreads();                                  // rowlist ready

  // ---- stage A (half hi) and B (half hj): 8+8 rows per wave, interleaved ----
  const int gsw = l >> 1;                           // 16B granule 0..31
  const int half8 = (l & 1) * 8;                    // byte offset in granule
  #pragma unroll 4
  for (int i = 0; i < 8; ++i) {
    const int r = w * 8 + i;                        // row-in-buffer 0..127
    const int ia = hi * 128 + r, ib = hj * 128 + r;
    const int growA = rowlistS[(ia < n) ? ia : 0];
    const int growB = rowlistS[(ib < n) ? ib : 0];
    const float4 va = *reinterpret_cast<const float4*>(E + (size_t)growA * DDIM + l * 4);
    const float4 vb = *reinterpret_cast<const float4*>(E + (size_t)growB * DDIM + l * 4);
    ushort4 ba, bb;
    ba.x = f2bf(va.x); ba.y = f2bf(va.y); ba.z = f2bf(va.z); ba.w = f2bf(va.w);
    bb.x = f2bf(vb.x); bb.y = f2bf(vb.y); bb.z = f2bf(vb.z); bb.w = f2bf(vb.w);
    const int off = r * 512 + ((gsw ^ (r & 15)) << 4) + half8;
    *reinterpret_cast<ushort4*>(As + off) = ba;
    *reinterpret_cast<ushort4*>(Bs + off) = bb;
  }
  __syncthreads();

  // ---- per-row sumsq from staged bf16 (4 threads per row, 256 rows) ----
  {
    const int rr = t >> 2, q8 = t & 3;              // rr 0..255
    const int r = rr & 127;
    const char* buf = (rr < 128) ? As : Bs;
    float q = 0.f;
    #pragma unroll
    for (int i = 0; i < 8; ++i) {
      const int gidx = q8 * 8 + i;
      const bfrag8 v = *reinterpret_cast<const bfrag8*>(
          buf + r * 512 + ((gidx ^ (r & 15)) << 4));
      #pragma unroll
      for (int e = 0; e < 8; ++e) {
        const float f = __uint_as_float(((unsigned)(unsigned short)v[e]) << 16);
        q = fmaf(f, f, q);
      }
    }
    q += __shfl_xor(q, 1);
    q += __shfl_xor(q, 2);
    if ((l & 3) == 0) { if (rr < 128) qA[r] = q; else qB[r] = q; }
  }
  __syncthreads();

  // ---- MFMA slab: 128x128 output, 16 waves as 4x4, 2x2 frags, K=256 ----
  const int wr = w >> 2, wc = w & 3;
  const int colsel = l & 15;
  const int ksel = l >> 4;

  f32x4 acc[2][2];
  const f32x4 zero = {0.f, 0.f, 0.f, 0.f};
  #pragma unroll
  for (int m = 0; m < 2; ++m)
    #pragma unroll
    for (int nn = 0; nn < 2; ++nn)
      acc[m][nn] = zero;

  #pragma unroll
  for (int kk = 0; kk < 8; ++kk) {
    bfrag8 af[2], bf[2];
    #pragma unroll
    for (int m = 0; m < 2; ++m) {
      const int row = wr * 32 + m * 16 + colsel;
      const int gidx = (kk * 4 + ksel) ^ (row & 15);
      af[m] = *reinterpret_cast<const bfrag8*>(As + row * 512 + (gidx << 4));
    }
    #pragma unroll
    for (int nn = 0; nn < 2; ++nn) {
      const int row = wc * 32 + nn * 16 + colsel;
      const int gidx = (kk * 4 + ksel) ^ (row & 15);
      bf[nn] = *reinterpret_cast<const bfrag8*>(Bs + row * 512 + (gidx << 4));
    }
    #pragma unroll
    for (int m = 0; m < 2; ++m)
      #pragma unroll
      for (int nn = 0; nn < 2; ++nn)
        acc[m][nn] = __builtin_amdgcn_mfma_f32_16x16x32_bf16(af[m], bf[nn],
                                                             acc[m][nn], 0, 0, 0);
  }

  // ---- epilogue: dist + validity/diag mask + reduce ----
  // C layout: col(lane&15)=B row, row((lane>>4)*4+reg)=A row [verified r1-6]
  float lsum = 0.f;
  #pragma unroll
  for (int m = 0; m < 2; ++m) {
    const int ar = wr * 32 + m * 16 + ksel * 4;     // A-buffer row base 0..127
    const int gi = hi * 128 + ar;                   // group-local i base
    const float q0 = qA[ar], q1 = qA[ar + 1], q2 = qA[ar + 2], q3 = qA[ar + 3];
    #pragma unroll
    for (int nn = 0; nn < 2; ++nn) {
      const int br = wc * 32 + nn * 16 + colsel;    // B-buffer row
      const int gj = hj * 128 + br;                 // group-local j
      const bool jv = gj < n;
      const float qj = qB[br];
      const f32x4 a = acc[m][nn];
      const float d0 = __builtin_amdgcn_sqrtf(fmaxf(q0 + qj - 2.f * a[0], 0.f));
      const float d1 = __builtin_amdgcn_sqrtf(fmaxf(q1 + qj - 2.f * a[1], 0.f));
      const float d2 = __builtin_amdgcn_sqrtf(fmaxf(q2 + qj - 2.f * a[2], 0.f));
      const float d3 = __builtin_amdgcn_sqrtf(fmaxf(q3 + qj - 2.f * a[3], 0.f));
      if (jv) {
        lsum += (gi + 0 < n && gi + 0 != gj) ? d0 : 0.f;
        lsum += (gi + 1 < n && gi + 1 != gj) ? d1 : 0.f;
        lsum += (gi + 2 < n && gi + 2 != gj) ? d2 : 0.f;
        lsum += (gi + 3 < n && gi + 3 != gj) ? d3 : 0.f;
      }
    }
  }
  #pragma unroll
  for (int o = 32; o; o >>= 1) lsum += __shfl_down(lsum, o);
  if (l == 0) wsum[w] = lsum;
  __syncthreads();

  // block sum via wave 0
  float blocksum = 0.f;
  if (w == 0) {
    float v = (l < 16) ? wsum[l] : 0.f;
    #pragma unroll
    for (int o = 8; o; o >>= 1) v += __shfl_down(v, o);
    blocksum = v;
  }

  // ---- publish partial + ticket; last block reduces in fixed order ----
  if (t == 0) {
    __hip_atomic_store(&partials[bid], blocksum, __ATOMIC_RELAXED,
                       __HIP_MEMORY_SCOPE_AGENT);
    const unsigned old = __hip_atomic_fetch_add(counter, 1u, __ATOMIC_ACQ_REL,
                                                __HIP_MEMORY_SCOPE_AGENT);
    lastS = (old == NBLK - 1) ? 1 : 0;
  }
  __syncthreads();
  if (lastS && t < 64) {
    const float p0 = __hip_atomic_load(&partials[t], __ATOMIC_RELAXED,
                                       __HIP_MEMORY_SCOPE_AGENT);
    const float p1 = __hip_atomic_load(&partials[t + 64], __ATOMIC_RELAXED,
                                       __HIP_MEMORY_SCOPE_AGENT);
    const float p2 = __hip_atomic_load(&partials[t + 128], __ATOMIC_RELAXED,
                                       __HIP_MEMORY_SCOPE_AGENT);
    const float p3 = __hip_atomic_load(&partials[t + 192], __ATOMIC_RELAXED,
                                       __HIP_MEMORY_SCOPE_AGENT);
    double s = (double)p0 + (double)p1 + (double)p2 + (double)p3;
    #pragma unroll
    for (int o = 32; o; o >>= 1) s += __shfl_down(s, o);
    if (t == 0) out[0] = (float)(s * invn);
  }
}

extern "C" void kernel_launch(void* const* d_in, const int* in_sizes, int n_in,
                              void* d_out, int out_size, void* d_ws, size_t ws_size,
                              hipStream_t stream) {
  const float* E = (const float*)d_in[0];
  const int* lab = (const int*)d_in[1];
  float* out = (float*)d_out;
  (void)n_in; (void)in_sizes; (void)out_size; (void)ws_size;

  char* ws = (char*)d_ws;
  float* partials = (float*)ws; ws += NBLK * sizeof(float);
  unsigned* counter = (unsigned*)ws;

  hipMemsetAsync(counter, 0, sizeof(unsigned), stream);  // graph-capturable node
  const double invn = 1.0 / ((double)NROWS * (double)(NROWS - 1));
  k_fused<<<NBLK, 1024, 0, stream>>>(E, lab, partials, counter, out, invn);
}